// Round 4
// baseline (36852.402 us; speedup 1.0000x reference)
//
#include <hip/hip_runtime.h>

// Problem constants
#define T_LEN 2048
#define I_DIM 128
#define H_DIM 256

// Partitioning: 8 groups (2 dir x 4 batch-tiles of 32) x 32 CUs.
// group = wg & 7, cu = wg >> 3. Each CU owns hidden cols [cu*8, cu*8+8).
//
// Per super-step s: LSTM(s) [s<T] and GRU(s-1) [s>=1] as bf16-split MFMA
// GEMMs. Exchange of h1(s), h2(s-1) via PLAIN stores in the A-fragment
// layout + one release fetch_add per CU on a per-group counter; consumers
// poll the counter, acquire-fence (buffer_inv), then load A-fragments
// DIRECTLY from the exchange buffer with plain dwordx4 loads (no LDS pass).
//
// Exchange buffer per (parity, group): 64KB =
//   plane-hi [32 kslice][1024B] at +0, plane-lo at +32768.
//   kslice ks2: 0..15 = h1 cols (j>>4), 16..31 = h2 cols. Within a slice:
//   [half=(j>>3)&1][32 b][8 e] bf16 -> lane*16 gives the A-frag for
//   mfma_32x32x16 (identical indexing to the LDS x staging).

// LDS offsets (bytes)
#define XHI_OFF 0               // x slices 0..7: 8*1024
#define XLO_OFF 8192
#define CRED_OFF 16384          // 4 x [32][33] f32 = 16896
#define HSTG_OFF 33280          // 4 x 512B (h1hi,h1lo,h2hi,h2lo) = 2048
#define LDS_BYTES 98304         // oversized on purpose: forces 1 WG/CU

typedef __attribute__((ext_vector_type(8))) short short8;
typedef __attribute__((ext_vector_type(16))) float f32x16;

__device__ __forceinline__ float sigmoidf_(float v) { return 1.f / (1.f + __expf(-v)); }
__device__ __forceinline__ float tanhf_fast(float v) {
    float t = __expf(-2.f * fabsf(v));
    float r = (1.f - t) / (1.f + t);
    return v < 0.f ? -r : r;
}
__device__ __forceinline__ unsigned short bf16_rne(float f) {
    unsigned u = __float_as_uint(f);
    return (unsigned short)((u + 0x7fffu + ((u >> 16) & 1u)) >> 16);
}
__device__ __forceinline__ void split2(float a, unsigned short& h, unsigned short& l) {
    h = bf16_rne(a);
    float hf = __uint_as_float(((unsigned)h) << 16);
    l = bf16_rne(a - hf);
}

__device__ __forceinline__ void stage_x_fn(const float* __restrict__ x, char* smem_b,
                                           int b0, int teff, int tid) {
    int b = tid >> 3, cq = tid & 7;   // b 0..31, cq = kslice 0..7
    const float4* src = (const float4*)(x + ((size_t)(b0 + b) * T_LEN + teff) * I_DIM + cq * 16);
    float4 v0 = src[0], v1 = src[1], v2 = src[2], v3 = src[3];
    float f[16] = {v0.x, v0.y, v0.z, v0.w, v1.x, v1.y, v1.z, v1.w,
                   v2.x, v2.y, v2.z, v2.w, v3.x, v3.y, v3.z, v3.w};
    short8 H0, H1, L0, L1;
    #pragma unroll
    for (int e = 0; e < 8; ++e) {
        unsigned short h, l;
        split2(f[e], h, l);      H0[e] = (short)h; L0[e] = (short)l;
        split2(f[8 + e], h, l);  H1[e] = (short)h; L1[e] = (short)l;
    }
    char* base = smem_b + cq * 1024 + b * 16;
    *(short8*)(base + XHI_OFF)       = H0;
    *(short8*)(base + XHI_OFF + 512) = H1;
    *(short8*)(base + XLO_OFF)       = L0;
    *(short8*)(base + XLO_OFF + 512) = L1;
}

__global__ __launch_bounds__(256, 1)
void brnn_persistent(const float* __restrict__ x,
                     const float* __restrict__ w1x, const float* __restrict__ b1x,
                     const float* __restrict__ w1h, const float* __restrict__ b1h,
                     const float* __restrict__ w2x, const float* __restrict__ b2x,
                     const float* __restrict__ w2h, const float* __restrict__ b2h,
                     int* cnts, char* exgb, float* h2out)
{
    extern __shared__ char smem_b[];

    const int tid  = threadIdx.x;
    const int lane = tid & 63;
    const int wid  = tid >> 6;         // wave 0..3
    const int wg   = blockIdx.x;
    const int grp  = wg & 7;
    const int cu   = wg >> 3;          // 0..31
    const int dir  = grp >> 2;
    const int btile = grp & 3;
    const int b0   = btile * 32;

    // ---------------- B-fragment preload (weights -> VGPRs, bf16 hi/lo) ------
    // wave0: LSTM kslices 0..11 (K 0..191: x + h1[0:64))
    // wave1: LSTM kslices 12..23 (K 192..383: h1[64:256))
    // wave2: GRU  h1 slices (kk 0..255; rows: r=w2x_r, z=w2x_z, xn=w2x_n, hn=0)
    // wave3: GRU  h2 slices (kk 0..255; rows: r=w2h_r, z=w2h_z, xn=0, hn=w2h_n)
    const int nrow = lane & 31;        // output row n
    const int jrow = nrow >> 2;        // j within CU slice
    const int q    = nrow & 3;         // gate index
    const int half = lane >> 5;        // k-half of slice
    short8 BH[16], BL[16];
    {
        #pragma unroll
        for (int i = 0; i < 16; ++i) {
            short8 H, L;
            #pragma unroll
            for (int e = 0; e < 8; ++e) {
                int kk = i * 16 + half * 8 + e;
                float v = 0.f;
                if (wid == 0) {
                    if (i < 12) {
                        int k = kk;
                        int R = q * H_DIM + cu * 8 + jrow;
                        v = (k < I_DIM) ? w1x[R * I_DIM + k] : w1h[R * H_DIM + (k - I_DIM)];
                    }
                } else if (wid == 1) {
                    if (i < 12) {
                        int k = 192 + kk;
                        int R = q * H_DIM + cu * 8 + jrow;
                        v = w1h[R * H_DIM + (k - I_DIM)];
                    }
                } else if (wid == 2) {
                    if (q < 3) v = w2x[(q * H_DIM + cu * 8 + jrow) * H_DIM + kk];
                } else {
                    if (q == 0)      v = w2h[(0 * H_DIM + cu * 8 + jrow) * H_DIM + kk];
                    else if (q == 1) v = w2h[(1 * H_DIM + cu * 8 + jrow) * H_DIM + kk];
                    else if (q == 3) v = w2h[(2 * H_DIM + cu * 8 + jrow) * H_DIM + kk];
                }
                unsigned short hh, ll;
                split2(v, hh, ll);
                H[e] = (short)hh; L[e] = (short)ll;
            }
            BH[i] = H; BL[i] = L;
        }
    }

    // ---------------- per-thread state-owner constants -----------------------
    const int bb = tid & 31;           // batch within tile
    const int jj = tid >> 5;           // j within CU slice (0..7)
    const float bi_ = b1x[0 * H_DIM + cu * 8 + jj] + b1h[0 * H_DIM + cu * 8 + jj];
    const float bf_ = b1x[1 * H_DIM + cu * 8 + jj] + b1h[1 * H_DIM + cu * 8 + jj];
    const float bg_ = b1x[2 * H_DIM + cu * 8 + jj] + b1h[2 * H_DIM + cu * 8 + jj];
    const float bo_ = b1x[3 * H_DIM + cu * 8 + jj] + b1h[3 * H_DIM + cu * 8 + jj];
    const float brz_r = b2x[0 * H_DIM + cu * 8 + jj] + b2h[0 * H_DIM + cu * 8 + jj];
    const float brz_z = b2x[1 * H_DIM + cu * 8 + jj] + b2h[1 * H_DIM + cu * 8 + jj];
    const float bnx_  = b2x[2 * H_DIM + cu * 8 + jj];
    const float bnh_  = b2h[2 * H_DIM + cu * 8 + jj];

    float c_reg = 0.f, h2_reg = 0.f;

    int* cnt = cnts + grp * 32;        // one padded counter per group

    // ---------------- init --------------------------------------------------
    // zero own h1 slice in parity-1 buffer (read by LSTM at s=0), both planes
    {
        char* p1 = exgb + (size_t)(1 * 8 + grp) * 65536;
        int off = (cu >> 1) * 1024 + (cu & 1) * 512;
        if (tid < 64) {
            *(unsigned long long*)(p1 + off + tid * 8) = 0ull;
            *(unsigned long long*)(p1 + 32768 + off + tid * 8) = 0ull;
        }
    }
    // zero HSTG h2 region (h2(-1) = 0, written out at end of s=0)
    if (tid < 128) *(unsigned long long*)(smem_b + HSTG_OFF + 1024 + tid * 8) = 0ull;
    stage_x_fn(x, smem_b, b0, dir ? (T_LEN - 1) : 0, tid);
    __syncthreads();   // drains init stores
    if (tid == 0)
        __hip_atomic_fetch_add(cnt, 1, __ATOMIC_RELEASE, __HIP_MEMORY_SCOPE_AGENT);

    for (int s = 0; s <= T_LEN; ++s) {
        // ---------------- wait for end-of-(s-1) data (or init for s=0) -------
        {
            int target = 32 * (s + 1);
            if (tid == 0) {
                while (__hip_atomic_load(cnt, __ATOMIC_RELAXED, __HIP_MEMORY_SCOPE_AGENT) < target)
                    __builtin_amdgcn_s_sleep(1);
                (void)__hip_atomic_load(cnt, __ATOMIC_ACQUIRE, __HIP_MEMORY_SCOPE_AGENT);
            }
            __syncthreads();
            if (lane == 0)   // per-wave acquire: buffer_inv before this wave's loads
                (void)__hip_atomic_load(cnt, __ATOMIC_ACQUIRE, __HIP_MEMORY_SCOPE_AGENT);
        }
        const char* exgR = exgb + (size_t)(((s + 1) & 1) * 8 + grp) * 65536;  // parity of s-1

        // ================= MFMA phase =================
        f32x16 accA, accB;
        #pragma unroll
        for (int r = 0; r < 16; ++r) { accA[r] = 0.f; accB[r] = 0.f; }

        if (wid < 2) {
            if (s < T_LEN) {
                #pragma unroll
                for (int i = 0; i < 12; ++i) {
                    int ks = wid * 12 + i;
                    short8 ah, al;
                    if (ks < 8) {
                        ah = *(const short8*)(smem_b + XHI_OFF + ks * 1024 + lane * 16);
                        al = *(const short8*)(smem_b + XLO_OFF + ks * 1024 + lane * 16);
                    } else {
                        int ks2 = ks - 8;   // h1 slices 0..15
                        ah = *(const short8*)(exgR + ks2 * 1024 + lane * 16);
                        al = *(const short8*)(exgR + 32768 + ks2 * 1024 + lane * 16);
                    }
                    if (i & 1) {
                        accB = __builtin_amdgcn_mfma_f32_32x32x16_bf16(ah, BH[i], accB, 0, 0, 0);
                        accB = __builtin_amdgcn_mfma_f32_32x32x16_bf16(ah, BL[i], accB, 0, 0, 0);
                        accB = __builtin_amdgcn_mfma_f32_32x32x16_bf16(al, BH[i], accB, 0, 0, 0);
                    } else {
                        accA = __builtin_amdgcn_mfma_f32_32x32x16_bf16(ah, BH[i], accA, 0, 0, 0);
                        accA = __builtin_amdgcn_mfma_f32_32x32x16_bf16(ah, BL[i], accA, 0, 0, 0);
                        accA = __builtin_amdgcn_mfma_f32_32x32x16_bf16(al, BH[i], accA, 0, 0, 0);
                    }
                }
            }
        } else {
            if (s >= 1) {
                #pragma unroll
                for (int i = 0; i < 16; ++i) {
                    int ks2 = (wid - 2) * 16 + i;   // wave2: h1 slices 0..15; wave3: h2 slices 16..31
                    short8 ah = *(const short8*)(exgR + ks2 * 1024 + lane * 16);
                    short8 al = *(const short8*)(exgR + 32768 + ks2 * 1024 + lane * 16);
                    if (i & 1) {
                        accB = __builtin_amdgcn_mfma_f32_32x32x16_bf16(ah, BH[i], accB, 0, 0, 0);
                        accB = __builtin_amdgcn_mfma_f32_32x32x16_bf16(ah, BL[i], accB, 0, 0, 0);
                        accB = __builtin_amdgcn_mfma_f32_32x32x16_bf16(al, BH[i], accB, 0, 0, 0);
                    } else {
                        accA = __builtin_amdgcn_mfma_f32_32x32x16_bf16(ah, BH[i], accA, 0, 0, 0);
                        accA = __builtin_amdgcn_mfma_f32_32x32x16_bf16(ah, BL[i], accA, 0, 0, 0);
                        accA = __builtin_amdgcn_mfma_f32_32x32x16_bf16(al, BH[i], accA, 0, 0, 0);
                    }
                }
            }
        }
        // write partial C -> cred[wid] ([32 n][33 b] f32)
        {
            float* credw = (float*)(smem_b + CRED_OFF) + wid * 1056;
            #pragma unroll
            for (int r = 0; r < 16; ++r) {
                int b = (r & 3) + 8 * (r >> 2) + 4 * half;
                credw[nrow * 33 + b] = accA[r] + accB[r];
            }
        }
        __syncthreads();

        // ================= nonlinearity phase =================
        const float* cr = (const float*)(smem_b + CRED_OFF);
        #define CRD(w, g) cr[(w) * 1056 + (jj * 4 + (g)) * 33 + bb]
        if (s < T_LEN) {
            float gi = CRD(0, 0) + CRD(1, 0) + bi_;
            float gf = CRD(0, 1) + CRD(1, 1) + bf_;
            float gg = CRD(0, 2) + CRD(1, 2) + bg_;
            float go = CRD(0, 3) + CRD(1, 3) + bo_;
            float ig = sigmoidf_(gi), fg = sigmoidf_(gf);
            float cg = tanhf_fast(gg), og = sigmoidf_(go);
            c_reg = c_reg * fg + ig * cg;
            float h1v = og * tanhf_fast(c_reg);
            unsigned short h, l;
            split2(h1v, h, l);
            *(unsigned short*)(smem_b + HSTG_OFF + bb * 16 + jj * 2) = h;
            *(unsigned short*)(smem_b + HSTG_OFF + 512 + bb * 16 + jj * 2) = l;
        }
        if (s >= 1) {
            float rc = CRD(2, 0) + CRD(3, 0) + brz_r;
            float zc = CRD(2, 1) + CRD(3, 1) + brz_z;
            float xn = CRD(2, 2) + CRD(3, 2) + bnx_;
            float hn = CRD(2, 3) + CRD(3, 3) + bnh_;
            float rg = sigmoidf_(rc), zg = sigmoidf_(zc);
            float ng = tanhf_fast(xn + rg * hn);
            h2_reg = zg * h2_reg + (1.f - zg) * ng;
            if (s == T_LEN) {
                h2out[(size_t)(grp * 32 + bb) * H_DIM + cu * 8 + jj] = h2_reg;
            } else {
                unsigned short h, l;
                split2(h2_reg, h, l);
                *(unsigned short*)(smem_b + HSTG_OFF + 1024 + bb * 16 + jj * 2) = h;
                *(unsigned short*)(smem_b + HSTG_OFF + 1536 + bb * 16 + jj * 2) = l;
            }
        }
        #undef CRD
        __syncthreads();

        if (s == T_LEN) break;

        // ================= exchange-out: plain 8B store per thread ============
        {
            char* exgW = exgb + (size_t)((s & 1) * 8 + grp) * 65536;
            unsigned long long v = *(const unsigned long long*)(smem_b + HSTG_OFF + tid * 8);
            int r = tid >> 6;                 // 0:h1hi 1:h1lo 2:h2hi 3:h2lo
            int w = (tid & 63) * 8;
            int off = (r & 1) * 32768 + ((r >> 1) * 16 + (cu >> 1)) * 1024 + (cu & 1) * 512 + w;
            *(unsigned long long*)(exgW + off) = v;
        }
        __syncthreads();   // every wave's stores drained (write-through to L2)
        if (tid == 0)      // wbl2 (L2 -> LLC) + arrival
            __hip_atomic_fetch_add(cnt, 1, __ATOMIC_RELEASE, __HIP_MEMORY_SCOPE_AGENT);
        // stage x(s+1): overlaps with peers' exchange
        if (s + 1 < T_LEN)
            stage_x_fn(x, smem_b, b0, dir ? (T_LEN - 2 - s) : (s + 1), tid);
    }
}

// out[b][o] = concat(h_fwd[b], h_bwd[b]) . wo[o] + bo[o]
__global__ __launch_bounds__(128)
void brnn_out(const float* __restrict__ h2out, const float* __restrict__ wo,
              const float* __restrict__ bo, float* __restrict__ out)
{
    __shared__ float hc[512];
    int b = blockIdx.x;
    int o = threadIdx.x;
    int btile = b >> 5, bi = b & 31;
    for (int k = threadIdx.x; k < 256; k += 128) {
        hc[k]       = h2out[((size_t)(btile)     * 32 + bi) * H_DIM + k];
        hc[256 + k] = h2out[((size_t)(4 + btile) * 32 + bi) * H_DIM + k];
    }
    __syncthreads();
    float acc = bo[o];
    const float4* w4 = (const float4*)&wo[(size_t)o * 512];
    #pragma unroll 8
    for (int k = 0; k < 128; ++k) {
        float4 w = w4[k];
        acc += w.x * hc[k * 4] + w.y * hc[k * 4 + 1] + w.z * hc[k * 4 + 2] + w.w * hc[k * 4 + 3];
    }
    out[b * 128 + o] = acc;
}

extern "C" void kernel_launch(void* const* d_in, const int* in_sizes, int n_in,
                              void* d_out, int out_size, void* d_ws, size_t ws_size,
                              hipStream_t stream) {
    const float* x   = (const float*)d_in[0];
    const float* w1x = (const float*)d_in[1];
    const float* b1x = (const float*)d_in[2];
    const float* w1h = (const float*)d_in[3];
    const float* b1h = (const float*)d_in[4];
    const float* w2x = (const float*)d_in[5];
    const float* b2x = (const float*)d_in[6];
    const float* w2h = (const float*)d_in[7];
    const float* b2h = (const float*)d_in[8];
    const float* wo  = (const float*)d_in[9];
    const float* bo  = (const float*)d_in[10];
    float* out = (float*)d_out;

    char* ws = (char*)d_ws;
    int* cnts = (int*)ws;                       // 8 padded counters in 32KB
    char* exgb = ws + 32768;                    // 2 par x 8 grp x 64KB = 1MB
    float* h2out = (float*)(ws + 32768 + 1048576);  // 256 x 256 f32 = 256KB

    hipMemsetAsync(cnts, 0, 8 * 32 * sizeof(int), stream);

    size_t shmem = LDS_BYTES;
    hipFuncSetAttribute((const void*)brnn_persistent,
                        hipFuncAttributeMaxDynamicSharedMemorySize, (int)shmem);

    void* args[] = { (void*)&x, (void*)&w1x, (void*)&b1x, (void*)&w1h, (void*)&b1h,
                     (void*)&w2x, (void*)&b2x, (void*)&w2h, (void*)&b2h,
                     (void*)&cnts, (void*)&exgb, (void*)&h2out };
    hipError_t err = hipLaunchCooperativeKernel((void*)brnn_persistent,
                                                dim3(256), dim3(256), args,
                                                (unsigned int)shmem, stream);
    if (err != hipSuccess) {
        brnn_persistent<<<dim3(256), dim3(256), shmem, stream>>>(
            x, w1x, b1x, w1h, b1h, w2x, b2x, w2h, b2h, cnts, exgb, h2out);
    }

    brnn_out<<<dim3(128), dim3(128), 0, stream>>>(h2out, wo, bo, out);
}

// Round 5
// 12989.438 us; speedup vs baseline: 2.8371x; 2.8371x over previous
//
#include <hip/hip_runtime.h>

// Problem constants
#define T_LEN 2048
#define I_DIM 128
#define H_DIM 256

// Partitioning: 8 groups (2 dir x 4 batch-tiles of 32) x 32 CUs.
// group = wg & 7, cu = wg >> 3. Each CU owns hidden cols [cu*8, cu*8+8).
//
// Super-step s: LSTM(s) [s<T] and GRU(s-1) [s>=1] as bf16 hi/lo-split MFMA
// GEMMs. All cross-CU data moves via RELAXED agent-scope atomics ONLY (no
// fences -> no buffer_inv/wbl2 cache storms; coherence at LLC per-access,
// the R3-proven model). MFMA A-fragments for h1/h2 are loaded DIRECTLY from
// the exchange buffer (no LDS staging pass).
//
// Exchange buffer per (parity, group): 64KB =
//   plane-hi [32 kslice][1024B] at +0, plane-lo at +32768.
//   kslice 0..15 = h1, 16..31 = h2. Within a slice: [2 half][32 b][8 e] bf16
//   -> lane*16 is the mfma_32x32x16 A-frag (same indexing as LDS x staging).

// LDS offsets (bytes)
#define XHI_OFF 0               // x slices 0..7: 8*1024
#define XLO_OFF 8192
#define CRED_OFF 16384          // 4 x [32][33] f32 = 16896
#define HSTG_OFF 33280          // 4 x 512B (h1hi,h1lo,h2hi,h2lo) = 2048
#define LDS_BYTES 98304         // oversized on purpose: forces 1 WG/CU

typedef __attribute__((ext_vector_type(8))) short short8;
typedef __attribute__((ext_vector_type(16))) float f32x16;

__device__ __forceinline__ float sigmoidf_(float v) { return 1.f / (1.f + __expf(-v)); }
__device__ __forceinline__ float tanhf_fast(float v) {
    float t = __expf(-2.f * fabsf(v));
    float r = (1.f - t) / (1.f + t);
    return v < 0.f ? -r : r;
}
__device__ __forceinline__ unsigned short bf16_rne(float f) {
    unsigned u = __float_as_uint(f);
    return (unsigned short)((u + 0x7fffu + ((u >> 16) & 1u)) >> 16);
}
__device__ __forceinline__ void split2(float a, unsigned short& h, unsigned short& l) {
    h = bf16_rne(a);
    float hf = __uint_as_float(((unsigned)h) << 16);
    l = bf16_rne(a - hf);
}

// 16B A-frag as two relaxed agent-scope u64 loads (coherent at LLC, no fence)
__device__ __forceinline__ short8 ld_frag(const char* p) {
    union { unsigned long long u[2]; short8 s; } v;
    v.u[0] = __hip_atomic_load((const unsigned long long*)p,
                               __ATOMIC_RELAXED, __HIP_MEMORY_SCOPE_AGENT);
    v.u[1] = __hip_atomic_load((const unsigned long long*)(p + 8),
                               __ATOMIC_RELAXED, __HIP_MEMORY_SCOPE_AGENT);
    return v.s;
}

__device__ __forceinline__ void stage_x_fn(const float* __restrict__ x, char* smem_b,
                                           int b0, int teff, int tid) {
    int b = tid >> 3, cq = tid & 7;   // b 0..31, cq = kslice 0..7
    const float4* src = (const float4*)(x + ((size_t)(b0 + b) * T_LEN + teff) * I_DIM + cq * 16);
    float4 v0 = src[0], v1 = src[1], v2 = src[2], v3 = src[3];
    float f[16] = {v0.x, v0.y, v0.z, v0.w, v1.x, v1.y, v1.z, v1.w,
                   v2.x, v2.y, v2.z, v2.w, v3.x, v3.y, v3.z, v3.w};
    short8 H0, H1, L0, L1;
    #pragma unroll
    for (int e = 0; e < 8; ++e) {
        unsigned short h, l;
        split2(f[e], h, l);      H0[e] = (short)h; L0[e] = (short)l;
        split2(f[8 + e], h, l);  H1[e] = (short)h; L1[e] = (short)l;
    }
    char* base = smem_b + cq * 1024 + b * 16;
    *(short8*)(base + XHI_OFF)       = H0;
    *(short8*)(base + XHI_OFF + 512) = H1;
    *(short8*)(base + XLO_OFF)       = L0;
    *(short8*)(base + XLO_OFF + 512) = L1;
}

#define MFMA3(ac, ah, al, bh, bl)                                              \
    ac = __builtin_amdgcn_mfma_f32_32x32x16_bf16(ah, bh, ac, 0, 0, 0);         \
    ac = __builtin_amdgcn_mfma_f32_32x32x16_bf16(ah, bl, ac, 0, 0, 0);         \
    ac = __builtin_amdgcn_mfma_f32_32x32x16_bf16(al, bh, ac, 0, 0, 0);

#define ACCSEL(i) ((i & 3) == 0 ? acc0 : (i & 3) == 1 ? acc1 : (i & 3) == 2 ? acc2 : acc3)

__global__ __launch_bounds__(256, 1)
void brnn_persistent(const float* __restrict__ x,
                     const float* __restrict__ w1x, const float* __restrict__ b1x,
                     const float* __restrict__ w1h, const float* __restrict__ b1h,
                     const float* __restrict__ w2x, const float* __restrict__ b2x,
                     const float* __restrict__ w2h, const float* __restrict__ b2h,
                     int* flags, char* exgb, float* h2out)
{
    extern __shared__ char smem_b[];

    const int tid  = threadIdx.x;
    const int lane = tid & 63;
    const int wid  = tid >> 6;         // wave 0..3
    const int wg   = blockIdx.x;
    const int grp  = wg & 7;
    const int cu   = wg >> 3;          // 0..31
    const int dir  = grp >> 2;
    const int btile = grp & 3;
    const int b0   = btile * 32;

    // ---------------- B-fragment preload (weights -> VGPRs, bf16 hi/lo) ------
    // wave0: LSTM K 0..191 (x 0..127, h1 0..63): A = x-slices 0..7 (LDS) + h1 slices 0..3
    // wave1: LSTM K 192..383 (h1 64..255): A = h1 slices 4..15
    // wave2: GRU h1 part (rows: r=w2x_r, z=w2x_z, xn=w2x_n, hn=0): h1 slices 0..15
    // wave3: GRU h2 part (rows: r=w2h_r, z=w2h_z, xn=0, hn=w2h_n): h2 slices 16..31
    const int nrow = lane & 31;        // output row n
    const int jrow = nrow >> 2;        // j within CU slice
    const int q    = nrow & 3;         // gate index
    const int half = lane >> 5;        // k-half of slice
    short8 BH[16], BL[16];
    {
        #pragma unroll
        for (int i = 0; i < 16; ++i) {
            short8 H, L;
            #pragma unroll
            for (int e = 0; e < 8; ++e) {
                int kk = i * 16 + half * 8 + e;
                float v = 0.f;
                if (wid == 0) {
                    if (i < 12) {
                        int k = kk;
                        int R = q * H_DIM + cu * 8 + jrow;
                        v = (k < I_DIM) ? w1x[R * I_DIM + k] : w1h[R * H_DIM + (k - I_DIM)];
                    }
                } else if (wid == 1) {
                    if (i < 12) {
                        int k = 192 + kk;
                        int R = q * H_DIM + cu * 8 + jrow;
                        v = w1h[R * H_DIM + (k - I_DIM)];
                    }
                } else if (wid == 2) {
                    if (q < 3) v = w2x[(q * H_DIM + cu * 8 + jrow) * H_DIM + kk];
                } else {
                    if (q == 0)      v = w2h[(0 * H_DIM + cu * 8 + jrow) * H_DIM + kk];
                    else if (q == 1) v = w2h[(1 * H_DIM + cu * 8 + jrow) * H_DIM + kk];
                    else if (q == 3) v = w2h[(2 * H_DIM + cu * 8 + jrow) * H_DIM + kk];
                }
                unsigned short hh, ll;
                split2(v, hh, ll);
                H[e] = (short)hh; L[e] = (short)ll;
            }
            BH[i] = H; BL[i] = L;
        }
    }

    // ---------------- per-thread state-owner constants -----------------------
    const int bb = tid & 31;           // batch within tile
    const int jj = tid >> 5;           // j within CU slice (0..7)
    const float bi_ = b1x[0 * H_DIM + cu * 8 + jj] + b1h[0 * H_DIM + cu * 8 + jj];
    const float bf_ = b1x[1 * H_DIM + cu * 8 + jj] + b1h[1 * H_DIM + cu * 8 + jj];
    const float bg_ = b1x[2 * H_DIM + cu * 8 + jj] + b1h[2 * H_DIM + cu * 8 + jj];
    const float bo_ = b1x[3 * H_DIM + cu * 8 + jj] + b1h[3 * H_DIM + cu * 8 + jj];
    const float brz_r = b2x[0 * H_DIM + cu * 8 + jj] + b2h[0 * H_DIM + cu * 8 + jj];
    const float brz_z = b2x[1 * H_DIM + cu * 8 + jj] + b2h[1 * H_DIM + cu * 8 + jj];
    const float bnx_  = b2x[2 * H_DIM + cu * 8 + jj];
    const float bnh_  = b2h[2 * H_DIM + cu * 8 + jj];

    float c_reg = 0.f, h2_reg = 0.f;

    // ---------------- init --------------------------------------------------
    // zero own h1 slice in parity-1 buffer (read at s=0), both planes, via
    // relaxed atomics (must be coherent with later atomic reads)
    {
        char* p1 = exgb + (size_t)(1 * 8 + grp) * 65536;
        int off = (cu >> 1) * 1024 + (cu & 1) * 512;
        if (tid < 64) {
            __hip_atomic_store((unsigned long long*)(p1 + off + tid * 8), 0ull,
                               __ATOMIC_RELAXED, __HIP_MEMORY_SCOPE_AGENT);
            __hip_atomic_store((unsigned long long*)(p1 + 32768 + off + tid * 8), 0ull,
                               __ATOMIC_RELAXED, __HIP_MEMORY_SCOPE_AGENT);
        }
    }
    // zero HSTG h2 region (h2(-1) = 0, published at end of s=0)
    if (tid < 128) *(unsigned long long*)(smem_b + HSTG_OFF + 1024 + tid * 8) = 0ull;
    stage_x_fn(x, smem_b, b0, dir ? (T_LEN - 1) : 0, tid);
    __syncthreads();   // drains init atomic stores (vmcnt)
    if (tid == 0)
        __hip_atomic_store(&flags[grp * 64 + cu], 1,
                           __ATOMIC_RELAXED, __HIP_MEMORY_SCOPE_AGENT);

    for (int s = 0; s <= T_LEN; ++s) {
        // ---------------- wait: packed per-CU flags, one-wave gather poll ----
        {
            int target = s + 1;
            if (tid < 64) {
                while (true) {
                    int v = (tid < 32)
                        ? __hip_atomic_load(&flags[grp * 64 + tid],
                                            __ATOMIC_RELAXED, __HIP_MEMORY_SCOPE_AGENT)
                        : 0x7fffffff;
                    if (__all(v >= target)) break;
                }
            }
            __syncthreads();
        }
        const char* exgR = exgb + (size_t)(((s + 1) & 1) * 8 + grp) * 65536;  // parity of s-1

        // ================= MFMA phase (loads-first, 4 acc chains) =============
        f32x16 acc0, acc1, acc2, acc3;
        #pragma unroll
        for (int r = 0; r < 16; ++r) { acc0[r] = 0.f; acc1[r] = 0.f; acc2[r] = 0.f; acc3[r] = 0.f; }

        if (wid == 0) {
            if (s < T_LEN) {
                short8 hA[4], lA[4];
                #pragma unroll
                for (int i = 0; i < 4; ++i) {
                    hA[i] = ld_frag(exgR + i * 1024 + lane * 16);
                    lA[i] = ld_frag(exgR + 32768 + i * 1024 + lane * 16);
                }
                #pragma unroll
                for (int i = 0; i < 8; ++i) {   // x part from LDS while h loads fly
                    short8 ah = *(const short8*)(smem_b + XHI_OFF + i * 1024 + lane * 16);
                    short8 al = *(const short8*)(smem_b + XLO_OFF + i * 1024 + lane * 16);
                    f32x16& ac = ACCSEL(i);
                    MFMA3(ac, ah, al, BH[i], BL[i]);
                }
                #pragma unroll
                for (int i = 0; i < 4; ++i) {
                    f32x16& ac = ACCSEL(8 + i);
                    MFMA3(ac, hA[i], lA[i], BH[8 + i], BL[8 + i]);
                }
            }
        } else if (wid == 1) {
            if (s < T_LEN) {
                short8 hA[12], lA[12];
                #pragma unroll
                for (int i = 0; i < 12; ++i) {
                    hA[i] = ld_frag(exgR + (4 + i) * 1024 + lane * 16);
                    lA[i] = ld_frag(exgR + 32768 + (4 + i) * 1024 + lane * 16);
                }
                #pragma unroll
                for (int i = 0; i < 12; ++i) {
                    f32x16& ac = ACCSEL(i);
                    MFMA3(ac, hA[i], lA[i], BH[i], BL[i]);
                }
            }
        } else {
            if (s >= 1) {
                const int sbase = (wid - 2) * 16;   // wave2: h1 slices 0..15; wave3: h2 16..31
                short8 hA[16], lA[16];
                #pragma unroll
                for (int i = 0; i < 16; ++i) {
                    hA[i] = ld_frag(exgR + (sbase + i) * 1024 + lane * 16);
                    lA[i] = ld_frag(exgR + 32768 + (sbase + i) * 1024 + lane * 16);
                }
                #pragma unroll
                for (int i = 0; i < 16; ++i) {
                    f32x16& ac = ACCSEL(i);
                    MFMA3(ac, hA[i], lA[i], BH[i], BL[i]);
                }
            }
        }
        // write partial C -> cred[wid] ([32 n][33 b] f32)
        {
            float* credw = (float*)(smem_b + CRED_OFF) + wid * 1056;
            #pragma unroll
            for (int r = 0; r < 16; ++r) {
                int b = (r & 3) + 8 * (r >> 2) + 4 * half;
                credw[nrow * 33 + b] = acc0[r] + acc1[r] + acc2[r] + acc3[r];
            }
        }
        __syncthreads();

        // ================= nonlinearity phase =================
        const float* cr = (const float*)(smem_b + CRED_OFF);
        #define CRD(w, g) cr[(w) * 1056 + (jj * 4 + (g)) * 33 + bb]
        if (s < T_LEN) {
            float gi = CRD(0, 0) + CRD(1, 0) + bi_;
            float gf = CRD(0, 1) + CRD(1, 1) + bf_;
            float gg = CRD(0, 2) + CRD(1, 2) + bg_;
            float go = CRD(0, 3) + CRD(1, 3) + bo_;
            float ig = sigmoidf_(gi), fg = sigmoidf_(gf);
            float cg = tanhf_fast(gg), og = sigmoidf_(go);
            c_reg = c_reg * fg + ig * cg;
            float h1v = og * tanhf_fast(c_reg);
            unsigned short h, l;
            split2(h1v, h, l);
            *(unsigned short*)(smem_b + HSTG_OFF + bb * 16 + jj * 2) = h;
            *(unsigned short*)(smem_b + HSTG_OFF + 512 + bb * 16 + jj * 2) = l;
        }
        if (s >= 1) {
            float rc = CRD(2, 0) + CRD(3, 0) + brz_r;
            float zc = CRD(2, 1) + CRD(3, 1) + brz_z;
            float xn = CRD(2, 2) + CRD(3, 2) + bnx_;
            float hn = CRD(2, 3) + CRD(3, 3) + bnh_;
            float rg = sigmoidf_(rc), zg = sigmoidf_(zc);
            float ng = tanhf_fast(xn + rg * hn);
            h2_reg = zg * h2_reg + (1.f - zg) * ng;
            if (s == T_LEN) {
                h2out[(size_t)(grp * 32 + bb) * H_DIM + cu * 8 + jj] = h2_reg;
            } else {
                unsigned short h, l;
                split2(h2_reg, h, l);
                *(unsigned short*)(smem_b + HSTG_OFF + 1024 + bb * 16 + jj * 2) = h;
                *(unsigned short*)(smem_b + HSTG_OFF + 1536 + bb * 16 + jj * 2) = l;
            }
        }
        #undef CRD
        __syncthreads();

        if (s == T_LEN) break;

        // ================= exchange-out: 1 relaxed atomic u64 store / thread ==
        {
            char* exgW = exgb + (size_t)((s & 1) * 8 + grp) * 65536;
            unsigned long long v = *(const unsigned long long*)(smem_b + HSTG_OFF + tid * 8);
            int r = tid >> 6;                 // 0:h1hi 1:h1lo 2:h2hi 3:h2lo
            int w = (tid & 63) * 8;
            int off = (r & 1) * 32768 + ((r >> 1) * 16 + (cu >> 1)) * 1024 + (cu & 1) * 512 + w;
            __hip_atomic_store((unsigned long long*)(exgW + off), v,
                               __ATOMIC_RELAXED, __HIP_MEMORY_SCOPE_AGENT);
        }
        __syncthreads();   // every wave's stores acked at LLC (vmcnt drain)
        if (tid == 0)
            __hip_atomic_store(&flags[grp * 64 + cu], s + 2,
                               __ATOMIC_RELAXED, __HIP_MEMORY_SCOPE_AGENT);
        // stage x(s+1) into LDS: overlaps peers' exchange + our wait
        if (s + 1 < T_LEN)
            stage_x_fn(x, smem_b, b0, dir ? (T_LEN - 2 - s) : (s + 1), tid);
    }
}

// out[b][o] = concat(h_fwd[b], h_bwd[b]) . wo[o] + bo[o]
__global__ __launch_bounds__(128)
void brnn_out(const float* __restrict__ h2out, const float* __restrict__ wo,
              const float* __restrict__ bo, float* __restrict__ out)
{
    __shared__ float hc[512];
    int b = blockIdx.x;
    int o = threadIdx.x;
    int btile = b >> 5, bi = b & 31;
    for (int k = threadIdx.x; k < 256; k += 128) {
        hc[k]       = h2out[((size_t)(btile)     * 32 + bi) * H_DIM + k];
        hc[256 + k] = h2out[((size_t)(4 + btile) * 32 + bi) * H_DIM + k];
    }
    __syncthreads();
    float acc = bo[o];
    const float4* w4 = (const float4*)&wo[(size_t)o * 512];
    #pragma unroll 8
    for (int k = 0; k < 128; ++k) {
        float4 w = w4[k];
        acc += w.x * hc[k * 4] + w.y * hc[k * 4 + 1] + w.z * hc[k * 4 + 2] + w.w * hc[k * 4 + 3];
    }
    out[b * 128 + o] = acc;
}

extern "C" void kernel_launch(void* const* d_in, const int* in_sizes, int n_in,
                              void* d_out, int out_size, void* d_ws, size_t ws_size,
                              hipStream_t stream) {
    const float* x   = (const float*)d_in[0];
    const float* w1x = (const float*)d_in[1];
    const float* b1x = (const float*)d_in[2];
    const float* w1h = (const float*)d_in[3];
    const float* b1h = (const float*)d_in[4];
    const float* w2x = (const float*)d_in[5];
    const float* b2x = (const float*)d_in[6];
    const float* w2h = (const float*)d_in[7];
    const float* b2h = (const float*)d_in[8];
    const float* wo  = (const float*)d_in[9];
    const float* bo  = (const float*)d_in[10];
    float* out = (float*)d_out;

    char* ws = (char*)d_ws;
    int* flags = (int*)ws;                      // 8 groups x 64 ints (32 used, packed)
    char* exgb = ws + 4096;                     // 2 par x 8 grp x 64KB = 1MB
    float* h2out = (float*)(ws + 4096 + 1048576);   // 256 x 256 f32 = 256KB

    hipMemsetAsync(flags, 0, 8 * 64 * sizeof(int), stream);

    size_t shmem = LDS_BYTES;
    hipFuncSetAttribute((const void*)brnn_persistent,
                        hipFuncAttributeMaxDynamicSharedMemorySize, (int)shmem);

    void* args[] = { (void*)&x, (void*)&w1x, (void*)&b1x, (void*)&w1h, (void*)&b1h,
                     (void*)&w2x, (void*)&b2x, (void*)&w2h, (void*)&b2h,
                     (void*)&flags, (void*)&exgb, (void*)&h2out };
    hipError_t err = hipLaunchCooperativeKernel((void*)brnn_persistent,
                                                dim3(256), dim3(256), args,
                                                (unsigned int)shmem, stream);
    if (err != hipSuccess) {
        brnn_persistent<<<dim3(256), dim3(256), shmem, stream>>>(
            x, w1x, b1x, w1h, b1h, w2x, b2x, w2h, b2h, flags, exgb, h2out);
    }

    brnn_out<<<dim3(128), dim3(128), 0, stream>>>(h2out, wo, bo, out);
}